// Round 1
// baseline (1214.826 us; speedup 1.0000x reference)
//
#include <hip/hip_runtime.h>

// RationalQuadratic: 4-layer MLP conditioner (bf16 MFMA GEMMs) + RQ spline.
// B=65536, D1=D2=64, DC=128, DFF=1024, NPP=23, K(spline)=8.
// GEMM chain: (B,256)@(256,1024) relu -> @(1024,1024) relu -> @(1024,1024) relu
//             -> @(1024,1472) -> params. N padded 1472->1536 for 128-col tiles.

typedef __bf16 bf16_t;
typedef __bf16 bf16x8 __attribute__((ext_vector_type(8)));
typedef float f32x4 __attribute__((ext_vector_type(4)));

#define GLOAD_LDS16(g, l)                                               \
  __builtin_amdgcn_global_load_lds(                                     \
      (const __attribute__((address_space(1))) void*)(g),               \
      (__attribute__((address_space(3))) void*)(l), 16, 0, 0)

// ---------------------------------------------------------------------------
// Weight convert+transpose: W (K,N) fp32 row-major -> Wt (Npad,K) bf16 row-major.
// grid (K/64, Npad/64), block 256. Zero-pads n >= N.
__global__ __launch_bounds__(256) void transpose_w(
    const float* __restrict__ W, bf16_t* __restrict__ Wt,
    int K, int N, int Npad) {
  __shared__ float tile[64][65];
  const int kt = blockIdx.x * 64;
  const int nt = blockIdx.y * 64;
  const int r4 = threadIdx.x >> 6;  // 0..3
  const int c = threadIdx.x & 63;
#pragma unroll
  for (int i = 0; i < 16; i++) {
    int r = i * 4 + r4;  // k-local
    int gn = nt + c;
    tile[r][c] = (gn < N) ? W[(size_t)(kt + r) * N + gn] : 0.0f;
  }
  __syncthreads();
#pragma unroll
  for (int i = 0; i < 16; i++) {
    int r = i * 4 + r4;  // n-local
    Wt[(size_t)(nt + r) * K + kt + c] = (bf16_t)tile[c][r];
  }
}

// ---------------------------------------------------------------------------
// X = concat(x1, mask1, context) as bf16, one chunk of Bc rows starting at boff.
// grid Bc blocks x 256 threads (one thread per element).
__global__ __launch_bounds__(256) void build_x(
    const float* __restrict__ x1, const float* __restrict__ mask1,
    const float* __restrict__ ctx, bf16_t* __restrict__ X, int boff) {
  int idx = blockIdx.x * 256 + threadIdx.x;
  int bl = idx >> 8;
  int c = idx & 255;
  size_t b = (size_t)(boff + bl);
  float v;
  if (c < 64)       v = x1[b * 64 + c];
  else if (c < 128) v = mask1[b * 64 + (c - 64)];
  else              v = ctx[b * 128 + (c - 128)];
  X[(size_t)bl * 256 + c] = (bf16_t)v;
}

// ---------------------------------------------------------------------------
// GEMM: C(M,N) = A(M,K) @ Bt(N,K)^T + bias, optional relu.
// m97 structure: 128x128 tile, BK=32, 4 waves in 2x2, each wave 4x4 of 16x16x32
// MFMA. global_load_lds width=16 staging (LDS dest = wave base + lane*16).
template <int RELU, int OUTF32>
__global__ __launch_bounds__(256) void gemm_bt(
    const bf16_t* __restrict__ A, const bf16_t* __restrict__ Bt,
    const float* __restrict__ bias, int Nbias,
    void* __restrict__ Cout, int M, int N, int K) {
  __shared__ __align__(16) bf16_t As[128 * 32];
  __shared__ __align__(16) bf16_t Bs[128 * 32];
  const int tid = threadIdx.x;
  const int w = tid >> 6;
  const int lane = tid & 63;
  const int m0 = blockIdx.y * 128;
  const int n0 = blockIdx.x * 128;
  const int wm = (w & 1) * 64;   // wave row offset in tile
  const int wn = (w >> 1) * 64;  // wave col offset in tile
  const int lrow = lane & 15;
  const int quad = lane >> 4;

  f32x4 acc[4][4];
#pragma unroll
  for (int i = 0; i < 4; i++)
#pragma unroll
    for (int j = 0; j < 4; j++) acc[i][j] = (f32x4){0.f, 0.f, 0.f, 0.f};

  // Staging geometry: tile = 8192B = 8 chunks of 1024B (64 lanes x 16B).
  // chunk = w*2 + c; byteoff = chunk*1024 + lane*16; row = byteoff/64 (64B rows
  // of 32 bf16, K-contiguous); element k offset = (byteoff&63)/2.
  const int nKt = K >> 5;
  for (int kt = 0; kt < nKt; kt++) {
    const int k0 = kt << 5;
#pragma unroll
    for (int c = 0; c < 2; c++) {
      const int chunk = w * 2 + c;
      const int byteoff = (chunk << 10) + lane * 16;
      const int row = byteoff >> 6;
      const int kel = (byteoff & 63) >> 1;
      const bf16_t* ga = A + (size_t)(m0 + row) * K + (k0 + kel);
      GLOAD_LDS16(ga, As + chunk * 512);
      const bf16_t* gb = Bt + (size_t)(n0 + row) * K + (k0 + kel);
      GLOAD_LDS16(gb, Bs + chunk * 512);
    }
    __syncthreads();  // drains vmcnt(0) -> LDS tiles ready
    bf16x8 af[4], bfr[4];
#pragma unroll
    for (int i = 0; i < 4; i++)
      af[i] = *(const bf16x8*)(As + (wm + i * 16 + lrow) * 32 + quad * 8);
#pragma unroll
    for (int j = 0; j < 4; j++)
      bfr[j] = *(const bf16x8*)(Bs + (wn + j * 16 + lrow) * 32 + quad * 8);
#pragma unroll
    for (int i = 0; i < 4; i++)
#pragma unroll
      for (int j = 0; j < 4; j++)
        acc[i][j] = __builtin_amdgcn_mfma_f32_16x16x32_bf16(af[i], bfr[j],
                                                            acc[i][j], 0, 0, 0);
    __syncthreads();  // all waves done reading before restage
  }

  // Epilogue. C/D layout (m89/m91 verified): col = lane&15, row = quad*4 + reg.
  float bv[4];
#pragma unroll
  for (int j = 0; j < 4; j++) {
    int col = n0 + wn + j * 16 + lrow;
    bv[j] = (col < Nbias) ? bias[col] : 0.0f;
  }
#pragma unroll
  for (int i = 0; i < 4; i++) {
    int rbase = m0 + wm + i * 16 + quad * 4;
#pragma unroll
    for (int j = 0; j < 4; j++) {
      int col = n0 + wn + j * 16 + lrow;
#pragma unroll
      for (int r = 0; r < 4; r++) {
        float v = acc[i][j][r] + bv[j];
        if (RELU) v = fmaxf(v, 0.0f);
        size_t off = (size_t)(rbase + r) * N + col;
        if (OUTF32)
          ((float*)Cout)[off] = v;
        else
          ((bf16_t*)Cout)[off] = (bf16_t)v;
      }
    }
  }
}

// ---------------------------------------------------------------------------
// RQ spline. One wave per batch row (lane = dim d, 64 dims). Reads 23 fp32
// params per (b,d) from P (row stride 1536), writes z2 and wave-reduced ld sum.
__global__ __launch_bounds__(256) void spline_kernel(
    const float* __restrict__ P, const float* __restrict__ x2,
    float* __restrict__ z_out, float* __restrict__ ld_out, int boff) {
  const int lane = threadIdx.x & 63;
  const int wid = threadIdx.x >> 6;
  const int bl = blockIdx.x * 4 + wid;
  const size_t b = (size_t)(boff + bl);

  const float* p = P + (size_t)bl * 1536 + lane * 23;
  float pr[23];
#pragma unroll
  for (int j = 0; j < 23; j++) pr[j] = p[j];
  const float x = x2[b * 64 + lane];

  const float SHIFT = 0.54132485f;     // log(e-1)
  const float SHIFT_DX = 5.1944682f;   // log(exp(6.0-0.8)-1)
  const float left = -3.0f;
  const float delta_x = 0.8f + log1pf(expf(SHIFT_DX));  // ~6.0, matches ref fp32
  const float right = left + delta_x;
  const float scale = delta_x;  // right-left == top-bottom (weight=1, bias=0)

  // widths: softmax(pr[0..7]) -> 0.1 + 0.2*softmax, cumsum scaled to [-3,3]
  float mw = pr[0];
#pragma unroll
  for (int j = 1; j < 8; j++) mw = fmaxf(mw, pr[j]);
  float ew[8], sw = 0.f;
#pragma unroll
  for (int j = 0; j < 8; j++) { ew[j] = expf(pr[j] - mw); sw += ew[j]; }
  float invw = 1.0f / sw;
  float cw[9];
  cw[0] = left;
  float cum = 0.f;
#pragma unroll
  for (int j = 0; j < 8; j++) {
    cum += 0.1f + 0.2f * ew[j] * invw;
    cw[j + 1] = left + scale * cum;
  }
  // heights
  float mh = pr[8];
#pragma unroll
  for (int j = 9; j < 16; j++) mh = fmaxf(mh, pr[j]);
  float eh[8], sh = 0.f;
#pragma unroll
  for (int j = 0; j < 8; j++) { eh[j] = expf(pr[8 + j] - mh); sh += eh[j]; }
  float invh = 1.0f / sh;
  float chh[9];
  chh[0] = left;  // bottom = weight*left + bias = -3
  float cumh = 0.f;
#pragma unroll
  for (int j = 0; j < 8; j++) {
    cumh += 0.1f + 0.2f * eh[j] * invh;
    chh[j + 1] = left + scale * cumh;
  }
  // derivs: [1, 0.001+softplus(d_raw+SHIFT) x7, 1]
  float dv[9];
  dv[0] = 1.0f;
  dv[8] = 1.0f;
#pragma unroll
  for (int j = 0; j < 7; j++) {
    float v = pr[16 + j] + SHIFT;
    dv[j + 1] = 0.001f + ((v > 20.f) ? v : log1pf(expf(v)));
  }

  // bin index: sum(bumped <= x) - 1, clipped to [0,7]
  int cnt = 0;
#pragma unroll
  for (int j = 0; j < 8; j++) cnt += (cw[j] <= x) ? 1 : 0;
  cnt += ((cw[8] + 1e-6f) <= x) ? 1 : 0;
  int idx = cnt - 1;
  idx = idx < 0 ? 0 : (idx > 7 ? 7 : idx);

  float x_k = cw[0], x_k1 = cw[1], y_k = chh[0], y_k1 = chh[1];
  float d0 = dv[0], d1 = dv[1];
#pragma unroll
  for (int j = 1; j < 8; j++) {
    bool s = (idx == j);
    x_k = s ? cw[j] : x_k;
    x_k1 = s ? cw[j + 1] : x_k1;
    y_k = s ? chh[j] : y_k;
    y_k1 = s ? chh[j + 1] : y_k1;
    d0 = s ? dv[j] : d0;
    d1 = s ? dv[j + 1] : d1;
  }
  float x_kd = x_k1 - x_k;
  float y_kd = y_k1 - y_k;
  float s_k = y_kd / x_kd;
  float xi = (x - x_k) / x_kd;
  float xi1m = xi * (1.f - xi);
  float alpha_k = y_kd * (s_k * xi * xi + d0 * xi1m);
  float beta_k = s_k + (d1 + d0 - 2.f * s_k) * xi1m;
  float z_sp = y_k + alpha_k / fmaxf(beta_k, 1e-8f);
  float oxi = 1.f - xi;
  float num = s_k * s_k * (d1 * xi * xi + 2.f * s_k * xi1m + d0 * oxi * oxi);
  float ld_sp = logf(fmaxf(num, 1e-8f)) - 2.f * logf(fmaxf(beta_k, 1e-8f));

  bool inside = (left <= x) && (x < right);
  float z = inside ? z_sp : x;     // z_af = exp(0)*x + 0
  float ld = inside ? ld_sp : 0.f; // ld_af = log_weight = 0

  z_out[b * 64 + lane] = z;
#pragma unroll
  for (int off = 32; off > 0; off >>= 1) ld += __shfl_down(ld, off);
  if (lane == 0) ld_out[b] = ld;
}

// ---------------------------------------------------------------------------
extern "C" void kernel_launch(void* const* d_in, const int* in_sizes, int n_in,
                              void* d_out, int out_size, void* d_ws,
                              size_t ws_size, hipStream_t stream) {
  const float* x1 = (const float*)d_in[0];
  const float* x2 = (const float*)d_in[1];
  const float* ctx = (const float*)d_in[2];
  const float* mask1 = (const float*)d_in[3];
  const float* W0 = (const float*)d_in[4];
  const float* b0 = (const float*)d_in[5];
  const float* W1 = (const float*)d_in[6];
  const float* b1 = (const float*)d_in[7];
  const float* W2 = (const float*)d_in[8];
  const float* b2 = (const float*)d_in[9];
  const float* W3 = (const float*)d_in[10];
  const float* b3 = (const float*)d_in[11];
  float* out = (float*)d_out;

  const int B = 65536;
  char* ws = (char*)d_ws;

  // Weight buffers (bf16, transposed to (Npad, K))
  bf16_t* Wt0 = (bf16_t*)ws;                            // 1024 x 256  (512 KB)
  bf16_t* Wt1 = (bf16_t*)(ws + 524288);                 // 1024 x 1024 (2 MB)
  bf16_t* Wt2 = (bf16_t*)(ws + 524288 + 2097152);       // 1024 x 1024 (2 MB)
  bf16_t* Wt3 = (bf16_t*)(ws + 524288 + 2 * 2097152);   // 1536 x 1024 (3 MB)
  const size_t wend = 524288 + 2 * 2097152 + 3145728;   // 7,864,320

  // Chunk B so activation buffers fit ws: per-row bytes = 512(X)+2048(HA)
  // +2048(HB)+6144(P fp32) = 10752.
  int C = 64;
  for (int c = 1; c <= 64; c <<= 1) {
    if (wend + (size_t)(B / c) * 10752 <= ws_size) { C = c; break; }
  }
  const int Bc = B / C;
  bf16_t* X = (bf16_t*)(ws + wend);
  bf16_t* HA = (bf16_t*)(ws + wend + (size_t)Bc * 512);
  bf16_t* HB = (bf16_t*)(ws + wend + (size_t)Bc * 512 + (size_t)Bc * 2048);
  float* P = (float*)(ws + wend + (size_t)Bc * 512 + (size_t)Bc * 2048 * 2);

  // Convert/transpose weights once per launch (ws is re-poisoned every call).
  transpose_w<<<dim3(4, 16), 256, 0, stream>>>(W0, Wt0, 256, 1024, 1024);
  transpose_w<<<dim3(16, 16), 256, 0, stream>>>(W1, Wt1, 1024, 1024, 1024);
  transpose_w<<<dim3(16, 16), 256, 0, stream>>>(W2, Wt2, 1024, 1024, 1024);
  transpose_w<<<dim3(16, 24), 256, 0, stream>>>(W3, Wt3, 1024, 1472, 1536);

  for (int c = 0; c < C; c++) {
    const int boff = c * Bc;
    build_x<<<Bc, 256, 0, stream>>>(x1, mask1, ctx, X, boff);
    gemm_bt<1, 0><<<dim3(8, Bc / 128), 256, 0, stream>>>(
        X, Wt0, b0, 1024, HA, Bc, 1024, 256);
    gemm_bt<1, 0><<<dim3(8, Bc / 128), 256, 0, stream>>>(
        HA, Wt1, b1, 1024, HB, Bc, 1024, 1024);
    gemm_bt<1, 0><<<dim3(8, Bc / 128), 256, 0, stream>>>(
        HB, Wt2, b2, 1024, HA, Bc, 1024, 1024);
    gemm_bt<0, 1><<<dim3(12, Bc / 128), 256, 0, stream>>>(
        HA, Wt3, b3, 1472, P, Bc, 1536, 1024);
    spline_kernel<<<Bc / 4, 256, 0, stream>>>(P, x2, out, out + (size_t)B * 64,
                                              boff);
  }
}